// Round 5
// baseline (374.940 us; speedup 1.0000x reference)
//
#include <hip/hip_runtime.h>
#include <math.h>

// 18-qubit statevector, 2 circuits + |<psi2|psi1>|^2, ONE persistent kernel.
// Qubit q (reference) <-> index bit (17-q). CZ chain diagonal:
// sign = parity(popc(i & (i>>1) & 0x1FFFF)).
//
// Structure (512 blocks x 256 thr, 2 blocks/CU co-resident, 5 grid barriers):
//   setup: compose all fused U = RZ*RY*RX (fp64 sincos) for own circuit into
//          LDS once; plus the 8 circuit-independent delta-RX gates.
//   P1:  layer-0 state is a PRODUCT state (closed form, no loads) + CZ0 +
//        layer-1 gates on set B.
//   P2..P5: leftover gates + CZ + next-layer gates (sets A,B,A,B).
//   P6:  layer-5 leftover collapses to 8 RX(th1-th2) gates on psi1 (RZ*RY and
//        CZ5 cancel in the overlap); dot against raw psi2 (blocks 0..255).
// Sets: A={0..9}, B={0,1}u{10..17}; 1024-amp chunks. Per thread 4 amps; lane
// bits 0..5 via shfl_xor, reg bits via 2 LDS rotations (M1: reg={8,9},
// M2: reg={6,7}).
// Grid barrier: monotone epoch counter in ws (zeroed by hipMemsetAsync),
// thread-0 fence/atomic/spin + __syncthreads (CG grid.sync pattern).

#define NQ      18
#define NSTATE  (1 << NQ)
#define SLOC    10
#define NL      (1 << SLOC)
#define TPB     256
#define NCHUNK  (NSTATE / NL)    // 256 chunks per circuit
#define NBLK    (2 * NCHUNK)     // 512 blocks

__device__ __forceinline__ float2 cmulf(float2 a, float2 b) {
    return make_float2(a.x * b.x - a.y * b.y, a.x * b.y + a.y * b.x);
}

__device__ __forceinline__ void compose_U(double cx, double sx, double cy,
                                          double sy, double zc, double zs,
                                          float2* up)
{
    double m00r = cy * cx,  m00i =  sy * sx;
    double m01r = -sy * cx, m01i = -cy * sx;
    double m10r = sy * cx,  m10i = -cy * sx;
    double m11r = cy * cx,  m11i = -sy * sx;
    up[0] = make_float2((float)(m00r * zc + m00i * zs), (float)(m00i * zc - m00r * zs));
    up[1] = make_float2((float)(m01r * zc + m01i * zs), (float)(m01i * zc - m01r * zs));
    up[2] = make_float2((float)(m10r * zc - m10i * zs), (float)(m10i * zc + m10r * zs));
    up[3] = make_float2((float)(m11r * zc - m11i * zs), (float)(m11i * zc + m11r * zs));
}

__device__ __forceinline__ void cpair(
    float& a0r, float& a0i, float& a1r, float& a1i,
    float u00r, float u00i, float u01r, float u01i,
    float u10r, float u10i, float u11r, float u11i)
{
    float n0r = u00r * a0r - u00i * a0i + u01r * a1r - u01i * a1i;
    float n0i = u00r * a0i + u00i * a0r + u01r * a1i + u01i * a1r;
    float n1r = u10r * a0r - u10i * a0i + u11r * a1r - u11i * a1i;
    float n1i = u10r * a0i + u10i * a0r + u11r * a1i + u11i * a1r;
    a0r = n0r; a0i = n0i; a1r = n1r; a1i = n1i;
}

template<int RB>
__device__ __forceinline__ void reg_gate(float (&ar)[4], float (&ai)[4],
                                         const float2* up)
{
    float u00r = up[0].x, u00i = up[0].y, u01r = up[1].x, u01i = up[1].y;
    float u10r = up[2].x, u10i = up[2].y, u11r = up[3].x, u11i = up[3].y;
#pragma unroll
    for (int r = 0; r < 4; ++r) {
        if (r & RB) continue;
        int r1 = r | RB;
        cpair(ar[r], ai[r], ar[r1], ai[r1],
              u00r, u00i, u01r, u01i, u10r, u10i, u11r, u11i);
    }
}

__device__ __forceinline__ void lane_gate(float (&ar)[4], float (&ai)[4],
                                          const float2* up, int lane, int j)
{
    float u00r = up[0].x, u00i = up[0].y, u01r = up[1].x, u01i = up[1].y;
    float u10r = up[2].x, u10i = up[2].y, u11r = up[3].x, u11i = up[3].y;
    int side = (lane >> j) & 1;
    float car = side ? u11r : u00r, cai = side ? u11i : u00i;
    float cbr = side ? u10r : u01r, cbi = side ? u10i : u01i;
#pragma unroll
    for (int r = 0; r < 4; ++r) {
        float pr = __shfl_xor(ar[r], 1 << j, 64);
        float pi = __shfl_xor(ai[r], 1 << j, 64);
        float mr = ar[r], mi = ai[r];
        ar[r] = car * mr - cai * mi + cbr * pr - cbi * pi;
        ai[r] = car * mi + cai * mr + cbr * pi + cbi * pr;
    }
}

__device__ __forceinline__ int gidx_f(int L, int g, int setB)
{
    return setB ? (((L >> 2) << 10) | (g << 2) | (L & 3)) : ((g << 10) | L);
}

__device__ __forceinline__ int cz_neg(int gi)
{
    return __popc(gi & (gi >> 1) & 0x1FFFF) & 1;
}

__device__ __forceinline__ void grid_barrier(unsigned* bar, unsigned epoch)
{
    __syncthreads();                 // drains vmcnt: all block stores issued
    if (threadIdx.x == 0) {
        __threadfence();             // release: write back dirty lines
        __hip_atomic_fetch_add(bar, 1u, __ATOMIC_ACQ_REL,
                               __HIP_MEMORY_SCOPE_AGENT);
        const unsigned target = epoch * NBLK;
        while (__hip_atomic_load(bar, __ATOMIC_RELAXED,
                                 __HIP_MEMORY_SCOPE_AGENT) < target)
            __builtin_amdgcn_s_sleep(1);
        __threadfence();             // acquire: invalidate stale lines
    }
    __syncthreads();
}

// ---------------- the mega kernel ------------------------------------------
__global__ __launch_bounds__(TPB, 2) void mega_kernel(
    float2* __restrict__ states,
    const float* __restrict__ x1, const float* __restrict__ x2,
    const float* __restrict__ iscale, const float* __restrict__ var,
    unsigned* __restrict__ bar, double* __restrict__ acc,
    unsigned* __restrict__ cnt2, float* __restrict__ out)
{
    __shared__ float2 sU[6][18][4];   // all fused gates, own circuit (3456 B)
    __shared__ float2 sDel[8][4];     // delta-RX for final pass
    __shared__ float sre[NL], sim[NL];
    __shared__ double wr[4], wi[4];

    int blk = blockIdx.x, t = threadIdx.x, lane = t & 63, wave = t >> 6;
    int circ = blk >> 8, g = blk & (NCHUNK - 1);
    float2* st = states + (size_t)circ * NSTATE;
    const float* xv = circ ? x2 : x1;

    // ---- one-time gate composition into LDS ----
    if (t < 108) {
        int layer = t / 18, gb = t % 18, q = 17 - gb;
        double tx = (double)iscale[layer * NQ + q] * (double)xv[q];
        double ty = (double)var[layer * 2 * NQ + q];
        double tz = (double)var[layer * 2 * NQ + NQ + q];
        double sx, cx, sy, cy, sz, cz;
        sincos(tx * 0.5, &sx, &cx);
        sincos(ty * 0.5, &sy, &cy);
        sincos(tz * 0.5, &sz, &cz);
        compose_U(cx, sx, cy, sy, cz, sz, &sU[layer][gb][0]);
    } else if (t < 116) {
        int j = t - 108, q = 15 - j;   // local bit 2+j (set A) -> q = 15-j
        double d = (double)iscale[5 * NQ + q] * ((double)x1[q] - (double)x2[q]);
        double sn, cs;
        sincos(d * 0.5, &sn, &cs);
        sDel[j][0] = make_float2((float)cs, 0.f);
        sDel[j][1] = make_float2(0.f, (float)-sn);
        sDel[j][2] = make_float2(0.f, (float)-sn);
        sDel[j][3] = make_float2((float)cs, 0.f);
    }
    __syncthreads();

    int Lm1[4], Lm2[4];
#pragma unroll
    for (int r = 0; r < 4; ++r) {
        Lm1[r] = (r << 8) | (wave << 6) | lane;   // M1: reg bits = local 8,9
        Lm2[r] = (wave << 8) | (r << 6) | lane;   // M2: reg bits = local 6,7
    }
    float ar[4], ai[4];

    // ---- P1: product state + CZ0 + layer-1 on set B ----
    {
        float2 com = make_float2(1.f, 0.f);
#pragma unroll
        for (int b = 2; b <= 9; ++b) {            // global bits 2..9 from g
            int bit = (g >> (b - 2)) & 1;
            com = cmulf(com, bit ? sU[0][b][2] : sU[0][b][0]);
        }
#pragma unroll
        for (int k = 0; k < 6; ++k) {             // lane bits -> global {0,1,10..13}
            int gb = k < 2 ? k : k + 8;
            int bit = (lane >> k) & 1;
            com = cmulf(com, bit ? sU[0][gb][2] : sU[0][gb][0]);
        }
        com = cmulf(com, (wave & 1) ? sU[0][16][2] : sU[0][16][0]);
        com = cmulf(com, ((wave >> 1) & 1) ? sU[0][17][2] : sU[0][17][0]);
#pragma unroll
        for (int r = 0; r < 4; ++r) {             // reg bits -> global 14,15
            float2 rf = cmulf((r & 1) ? sU[0][14][2] : sU[0][14][0],
                              ((r >> 1) & 1) ? sU[0][15][2] : sU[0][15][0]);
            float2 a = cmulf(com, rf);
            ar[r] = a.x; ai[r] = a.y;
        }
#pragma unroll
        for (int r = 0; r < 4; ++r)               // CZ0
            if (cz_neg(gidx_f(Lm2[r], g, 1))) { ar[r] = -ar[r]; ai[r] = -ai[r]; }
        lane_gate(ar, ai, sU[1][0],  lane, 0);
        lane_gate(ar, ai, sU[1][1],  lane, 1);
        lane_gate(ar, ai, sU[1][10], lane, 2);
        lane_gate(ar, ai, sU[1][11], lane, 3);
        lane_gate(ar, ai, sU[1][12], lane, 4);
        lane_gate(ar, ai, sU[1][13], lane, 5);
        reg_gate<1>(ar, ai, sU[1][14]);
        reg_gate<2>(ar, ai, sU[1][15]);
#pragma unroll
        for (int r = 0; r < 4; ++r) { sre[Lm2[r]] = ar[r]; sim[Lm2[r]] = ai[r]; }
        __syncthreads();
#pragma unroll
        for (int r = 0; r < 4; ++r) { ar[r] = sre[Lm1[r]]; ai[r] = sim[Lm1[r]]; }
        reg_gate<1>(ar, ai, sU[1][16]);
        reg_gate<2>(ar, ai, sU[1][17]);
#pragma unroll
        for (int r = 0; r < 4; ++r)
            st[gidx_f(Lm1[r], g, 1)] = make_float2(ar[r], ai[r]);
    }
    grid_barrier(bar, 1);

    // ---- P2..P5: leftover(pl) + CZ(pl) + layer(nl) ----
    const int tbl[4][3] = { {0, 1, 2}, {1, 2, 3}, {0, 3, 4}, {1, 4, 5} };
    for (int p = 0; p < 4; ++p) {
        int setB = tbl[p][0], pl = tbl[p][1], nl = tbl[p][2];
        float2 v4[4];
#pragma unroll
        for (int r = 0; r < 4; ++r) v4[r] = st[gidx_f(Lm1[r], g, setB)];
        auto GB = [&](int s) { return setB ? (s < 2 ? s : s + 8) : s; };
#pragma unroll
        for (int r = 0; r < 4; ++r) { ar[r] = v4[r].x; ai[r] = v4[r].y; }
        // phase 1 (M1): prev lane 2..5, reg 8,9
        lane_gate(ar, ai, sU[pl][GB(2)], lane, 2);
        lane_gate(ar, ai, sU[pl][GB(3)], lane, 3);
        lane_gate(ar, ai, sU[pl][GB(4)], lane, 4);
        lane_gate(ar, ai, sU[pl][GB(5)], lane, 5);
        reg_gate<1>(ar, ai, sU[pl][GB(8)]);
        reg_gate<2>(ar, ai, sU[pl][GB(9)]);
        // rotate M1 -> M2
#pragma unroll
        for (int r = 0; r < 4; ++r) { sre[Lm1[r]] = ar[r]; sim[Lm1[r]] = ai[r]; }
        __syncthreads();
#pragma unroll
        for (int r = 0; r < 4; ++r) { ar[r] = sre[Lm2[r]]; ai[r] = sim[Lm2[r]]; }
        // phase 2 (M2): prev reg 6,7; CZ; next lane 0..5 + reg 6,7
        reg_gate<1>(ar, ai, sU[pl][GB(6)]);
        reg_gate<2>(ar, ai, sU[pl][GB(7)]);
#pragma unroll
        for (int r = 0; r < 4; ++r)
            if (cz_neg(gidx_f(Lm2[r], g, setB))) { ar[r] = -ar[r]; ai[r] = -ai[r]; }
        lane_gate(ar, ai, sU[nl][GB(0)], lane, 0);
        lane_gate(ar, ai, sU[nl][GB(1)], lane, 1);
        lane_gate(ar, ai, sU[nl][GB(2)], lane, 2);
        lane_gate(ar, ai, sU[nl][GB(3)], lane, 3);
        lane_gate(ar, ai, sU[nl][GB(4)], lane, 4);
        lane_gate(ar, ai, sU[nl][GB(5)], lane, 5);
        reg_gate<1>(ar, ai, sU[nl][GB(6)]);
        reg_gate<2>(ar, ai, sU[nl][GB(7)]);
        // rotate M2 -> M1 (slots thread-exclusive: no pre-barrier needed)
#pragma unroll
        for (int r = 0; r < 4; ++r) { sre[Lm2[r]] = ar[r]; sim[Lm2[r]] = ai[r]; }
        __syncthreads();
#pragma unroll
        for (int r = 0; r < 4; ++r) { ar[r] = sre[Lm1[r]]; ai[r] = sim[Lm1[r]]; }
        // phase 3 (M1): next reg 8,9, store
        reg_gate<1>(ar, ai, sU[nl][GB(8)]);
        reg_gate<2>(ar, ai, sU[nl][GB(9)]);
#pragma unroll
        for (int r = 0; r < 4; ++r)
            st[gidx_f(Lm1[r], g, setB)] = make_float2(ar[r], ai[r]);
        grid_barrier(bar, 2 + p);
    }

    // ---- P6: delta-RX on psi1, dot with raw psi2 (blocks 0..255) ----
    if (blk < NCHUNK) {
        const float2* s1 = states;
        const float2* s2 = states + NSTATE;
        float2 v1[4], v2[4];
#pragma unroll
        for (int r = 0; r < 4; ++r) {
            v1[r] = s1[(g << 10) | Lm1[r]];
            v2[r] = s2[(g << 10) | Lm2[r]];
        }
#pragma unroll
        for (int r = 0; r < 4; ++r) { ar[r] = v1[r].x; ai[r] = v1[r].y; }
        lane_gate(ar, ai, sDel[0], lane, 2);
        lane_gate(ar, ai, sDel[1], lane, 3);
        lane_gate(ar, ai, sDel[2], lane, 4);
        lane_gate(ar, ai, sDel[3], lane, 5);
        reg_gate<1>(ar, ai, sDel[6]);
        reg_gate<2>(ar, ai, sDel[7]);
#pragma unroll
        for (int r = 0; r < 4; ++r) { sre[Lm1[r]] = ar[r]; sim[Lm1[r]] = ai[r]; }
        __syncthreads();
#pragma unroll
        for (int r = 0; r < 4; ++r) { ar[r] = sre[Lm2[r]]; ai[r] = sim[Lm2[r]]; }
        reg_gate<1>(ar, ai, sDel[4]);
        reg_gate<2>(ar, ai, sDel[5]);
        double accr = 0.0, acci = 0.0;
#pragma unroll
        for (int r = 0; r < 4; ++r) {
            accr += (double)v2[r].x * ar[r] + (double)v2[r].y * ai[r];
            acci += (double)v2[r].x * ai[r] - (double)v2[r].y * ar[r];
        }
        for (int o = 32; o > 0; o >>= 1) {
            accr += __shfl_down(accr, o, 64);
            acci += __shfl_down(acci, o, 64);
        }
        if (lane == 0) { wr[wave] = accr; wi[wave] = acci; }
        __syncthreads();
        if (t == 0) {
            double br = wr[0] + wr[1] + wr[2] + wr[3];
            double bi = wi[0] + wi[1] + wi[2] + wi[3];
            atomicAdd(&acc[0], br);
            atomicAdd(&acc[1], bi);
            __threadfence();
            unsigned old = atomicAdd(cnt2, 1u);
            if (old == NCHUNK - 1) {
                double fr = atomicAdd(&acc[0], 0.0);
                double fi = atomicAdd(&acc[1], 0.0);
                out[0] = (float)(fr * fr + fi * fi);
            }
        }
    }
}

// ---------------- launch ----------------------------------------------------
extern "C" void kernel_launch(void* const* d_in, const int* in_sizes, int n_in,
                              void* d_out, int out_size, void* d_ws, size_t ws_size,
                              hipStream_t stream)
{
    const float* x1 = (const float*)d_in[0];
    const float* x2 = (const float*)d_in[1];
    const float* iscale = (const float*)d_in[2];
    const float* var = (const float*)d_in[3];
    float* out = (float*)d_out;

    // ws layout: [8192,8208) acc (2 doubles); [8208,8212) bar; [8212,8216) cnt2;
    // [16384, 16384+4MB) statevectors.
    double*   acc    = (double*)((char*)d_ws + 8192);
    unsigned* bar    = (unsigned*)((char*)d_ws + 8208);
    unsigned* cnt2   = (unsigned*)((char*)d_ws + 8212);
    float2*   states = (float2*)((char*)d_ws + 16384);

    // zero barrier/accumulator state (graph-capturable memset node)
    hipMemsetAsync((char*)d_ws + 8192, 0, 32, stream);

    mega_kernel<<<NBLK, TPB, 0, stream>>>(states, x1, x2, iscale, var,
                                          bar, acc, cnt2, out);
}

// Round 6
// 265.931 us; speedup vs baseline: 1.4099x; 1.4099x over previous
//
#include <hip/hip_runtime.h>
#include <math.h>

// 18-qubit statevector, 2 circuits + |<psi2|psi1>|^2, ONE persistent kernel.
// Qubit q (reference) <-> index bit (17-q). CZ chain diagonal:
// sign = parity(popc(i & (i>>1) & 0x1FFFF)).
//
// 256 blocks x 256 thr (1 block/CU -> unconditional co-residency), each block
// handles chunk g of BOTH circuits sequentially per pass. 5 grid barriers
// (system-scope atomics: release fetch_add + ACQUIRE spin load reading the
// coherent LLC, s_sleep backoff).
//   setup: compose all 216 fused U = RZ*RY*RX (fp64 sincos) into LDS once,
//          plus the 8 circuit-independent delta-RX gates.
//   P1:  layer-0 state is a PRODUCT state (closed form, no loads) + CZ0 +
//        layer-1 gates on set B.
//   P2..P5: leftover gates + CZ + next-layer gates (sets A,B,A,B).
//   P6:  layer-5 leftover collapses to 8 RX(th1-th2) gates on psi1 (RZ*RY and
//        CZ5 cancel in the overlap); dot against raw psi2.
// Sets: A={0..9}, B={0,1}u{10..17}; 1024-amp chunks. Per thread 4 amps; lane
// bits 0..5 via shfl_xor, reg bits via 2 LDS rotations (M1: reg={8,9},
// M2: reg={6,7}). Leftover gates are always local bits 2..9.

#define NQ      18
#define NSTATE  (1 << NQ)
#define SLOC    10
#define NL      (1 << SLOC)
#define TPB     256
#define NCHUNK  (NSTATE / NL)    // 256 chunks per circuit
#define NBLK    NCHUNK           // 256 blocks, 1 per CU

__device__ __forceinline__ float2 cmulf(float2 a, float2 b) {
    return make_float2(a.x * b.x - a.y * b.y, a.x * b.y + a.y * b.x);
}

__device__ __forceinline__ void compose_U(double cx, double sx, double cy,
                                          double sy, double zc, double zs,
                                          float2* up)
{
    double m00r = cy * cx,  m00i =  sy * sx;
    double m01r = -sy * cx, m01i = -cy * sx;
    double m10r = sy * cx,  m10i = -cy * sx;
    double m11r = cy * cx,  m11i = -sy * sx;
    up[0] = make_float2((float)(m00r * zc + m00i * zs), (float)(m00i * zc - m00r * zs));
    up[1] = make_float2((float)(m01r * zc + m01i * zs), (float)(m01i * zc - m01r * zs));
    up[2] = make_float2((float)(m10r * zc - m10i * zs), (float)(m10i * zc + m10r * zs));
    up[3] = make_float2((float)(m11r * zc - m11i * zs), (float)(m11i * zc + m11r * zs));
}

__device__ __forceinline__ void cpair(
    float& a0r, float& a0i, float& a1r, float& a1i,
    float u00r, float u00i, float u01r, float u01i,
    float u10r, float u10i, float u11r, float u11i)
{
    float n0r = u00r * a0r - u00i * a0i + u01r * a1r - u01i * a1i;
    float n0i = u00r * a0i + u00i * a0r + u01r * a1i + u01i * a1r;
    float n1r = u10r * a0r - u10i * a0i + u11r * a1r - u11i * a1i;
    float n1i = u10r * a0i + u10i * a0r + u11r * a1i + u11i * a1r;
    a0r = n0r; a0i = n0i; a1r = n1r; a1i = n1i;
}

template<int RB>
__device__ __forceinline__ void reg_gate(float (&ar)[4], float (&ai)[4],
                                         const float2* up)
{
    float u00r = up[0].x, u00i = up[0].y, u01r = up[1].x, u01i = up[1].y;
    float u10r = up[2].x, u10i = up[2].y, u11r = up[3].x, u11i = up[3].y;
#pragma unroll
    for (int r = 0; r < 4; ++r) {
        if (r & RB) continue;
        int r1 = r | RB;
        cpair(ar[r], ai[r], ar[r1], ai[r1],
              u00r, u00i, u01r, u01i, u10r, u10i, u11r, u11i);
    }
}

__device__ __forceinline__ void lane_gate(float (&ar)[4], float (&ai)[4],
                                          const float2* up, int lane, int j)
{
    float u00r = up[0].x, u00i = up[0].y, u01r = up[1].x, u01i = up[1].y;
    float u10r = up[2].x, u10i = up[2].y, u11r = up[3].x, u11i = up[3].y;
    int side = (lane >> j) & 1;
    float car = side ? u11r : u00r, cai = side ? u11i : u00i;
    float cbr = side ? u10r : u01r, cbi = side ? u10i : u01i;
#pragma unroll
    for (int r = 0; r < 4; ++r) {
        float pr = __shfl_xor(ar[r], 1 << j, 64);
        float pi = __shfl_xor(ai[r], 1 << j, 64);
        float mr = ar[r], mi = ai[r];
        ar[r] = car * mr - cai * mi + cbr * pr - cbi * pi;
        ai[r] = car * mi + cai * mr + cbr * pi + cbi * pr;
    }
}

__device__ __forceinline__ int gidx_f(int L, int g, int setB)
{
    return setB ? (((L >> 2) << 10) | (g << 2) | (L & 3)) : ((g << 10) | L);
}

__device__ __forceinline__ int cz_neg(int gi)
{
    return __popc(gi & (gi >> 1) & 0x1FFFF) & 1;
}

// system-scope grid barrier: counter lives in LLC (coherent across XCDs)
__device__ __forceinline__ void grid_barrier(unsigned* bar, unsigned epoch)
{
    __syncthreads();
    if (threadIdx.x == 0) {
        __threadfence();   // publish this block's stores (L2 writeback)
        __hip_atomic_fetch_add(bar, 1u, __ATOMIC_RELEASE,
                               __HIP_MEMORY_SCOPE_SYSTEM);
        const unsigned target = epoch * NBLK;
        while (__hip_atomic_load(bar, __ATOMIC_ACQUIRE,
                                 __HIP_MEMORY_SCOPE_SYSTEM) < target)
            __builtin_amdgcn_s_sleep(2);
        __threadfence();   // invalidate stale L2 before re-reading
    }
    __syncthreads();
}

// ---------------- the mega kernel ------------------------------------------
__global__ __launch_bounds__(TPB, 1) void mega_kernel(
    float2* __restrict__ states,
    const float* __restrict__ x1, const float* __restrict__ x2,
    const float* __restrict__ iscale, const float* __restrict__ var,
    unsigned* __restrict__ bar, double* __restrict__ acc,
    unsigned* __restrict__ cnt2, float* __restrict__ out)
{
    __shared__ float2 sU[2][6][18][4];   // all fused gates, both circuits (6912 B)
    __shared__ float2 sDel[8][4];        // delta-RX for final pass
    __shared__ float sre[NL], sim[NL];
    __shared__ double wr[4], wi[4];

    int g = blockIdx.x, t = threadIdx.x, lane = t & 63, wave = t >> 6;

    // ---- one-time gate composition into LDS (both circuits) ----
    if (t < 216) {
        int c = t / 108, rem = t % 108;
        int layer = rem / 18, gb = rem % 18, q = 17 - gb;
        const float* xv = c ? x2 : x1;
        double tx = (double)iscale[layer * NQ + q] * (double)xv[q];
        double ty = (double)var[layer * 2 * NQ + q];
        double tz = (double)var[layer * 2 * NQ + NQ + q];
        double sx, cx, sy, cy, sz, cz;
        sincos(tx * 0.5, &sx, &cx);
        sincos(ty * 0.5, &sy, &cy);
        sincos(tz * 0.5, &sz, &cz);
        compose_U(cx, sx, cy, sy, cz, sz, &sU[c][layer][gb][0]);
    } else if (t < 224) {
        int j = t - 216, q = 15 - j;   // local bit 2+j (set A) -> q = 15-j
        double d = (double)iscale[5 * NQ + q] * ((double)x1[q] - (double)x2[q]);
        double sn, cs;
        sincos(d * 0.5, &sn, &cs);
        sDel[j][0] = make_float2((float)cs, 0.f);
        sDel[j][1] = make_float2(0.f, (float)-sn);
        sDel[j][2] = make_float2(0.f, (float)-sn);
        sDel[j][3] = make_float2((float)cs, 0.f);
    }
    __syncthreads();

    int Lm1[4], Lm2[4];
#pragma unroll
    for (int r = 0; r < 4; ++r) {
        Lm1[r] = (r << 8) | (wave << 6) | lane;   // M1: reg bits = local 8,9
        Lm2[r] = (wave << 8) | (r << 6) | lane;   // M2: reg bits = local 6,7
    }
    float ar[4], ai[4];

    // ---- P1: product state + CZ0 + layer-1 on set B (both circuits) ----
    for (int c = 0; c < 2; ++c) {
        float2* st = states + (size_t)c * NSTATE;
        float2 com = make_float2(1.f, 0.f);
#pragma unroll
        for (int b = 2; b <= 9; ++b) {            // global bits 2..9 from g
            int bit = (g >> (b - 2)) & 1;
            com = cmulf(com, bit ? sU[c][0][b][2] : sU[c][0][b][0]);
        }
#pragma unroll
        for (int k = 0; k < 6; ++k) {             // lane bits -> global {0,1,10..13}
            int gb = k < 2 ? k : k + 8;
            int bit = (lane >> k) & 1;
            com = cmulf(com, bit ? sU[c][0][gb][2] : sU[c][0][gb][0]);
        }
        com = cmulf(com, (wave & 1) ? sU[c][0][16][2] : sU[c][0][16][0]);
        com = cmulf(com, ((wave >> 1) & 1) ? sU[c][0][17][2] : sU[c][0][17][0]);
#pragma unroll
        for (int r = 0; r < 4; ++r) {             // reg bits -> global 14,15
            float2 rf = cmulf((r & 1) ? sU[c][0][14][2] : sU[c][0][14][0],
                              ((r >> 1) & 1) ? sU[c][0][15][2] : sU[c][0][15][0]);
            float2 a = cmulf(com, rf);
            ar[r] = a.x; ai[r] = a.y;
        }
#pragma unroll
        for (int r = 0; r < 4; ++r)               // CZ0
            if (cz_neg(gidx_f(Lm2[r], g, 1))) { ar[r] = -ar[r]; ai[r] = -ai[r]; }
        lane_gate(ar, ai, sU[c][1][0],  lane, 0);
        lane_gate(ar, ai, sU[c][1][1],  lane, 1);
        lane_gate(ar, ai, sU[c][1][10], lane, 2);
        lane_gate(ar, ai, sU[c][1][11], lane, 3);
        lane_gate(ar, ai, sU[c][1][12], lane, 4);
        lane_gate(ar, ai, sU[c][1][13], lane, 5);
        reg_gate<1>(ar, ai, sU[c][1][14]);
        reg_gate<2>(ar, ai, sU[c][1][15]);
        // rotate M2 -> M1 (slot writes are thread-owned in both mappings)
#pragma unroll
        for (int r = 0; r < 4; ++r) { sre[Lm2[r]] = ar[r]; sim[Lm2[r]] = ai[r]; }
        __syncthreads();
#pragma unroll
        for (int r = 0; r < 4; ++r) { ar[r] = sre[Lm1[r]]; ai[r] = sim[Lm1[r]]; }
        reg_gate<1>(ar, ai, sU[c][1][16]);
        reg_gate<2>(ar, ai, sU[c][1][17]);
#pragma unroll
        for (int r = 0; r < 4; ++r)
            st[gidx_f(Lm1[r], g, 1)] = make_float2(ar[r], ai[r]);
    }
    grid_barrier(bar, 1);

    // ---- P2..P5: leftover(pl) + CZ(pl) + layer(nl), both circuits ----
    const int tbl[4][3] = { {0, 1, 2}, {1, 2, 3}, {0, 3, 4}, {1, 4, 5} };
    for (int p = 0; p < 4; ++p) {
        int setB = tbl[p][0], pl = tbl[p][1], nl = tbl[p][2];
        for (int c = 0; c < 2; ++c) {
            float2* st = states + (size_t)c * NSTATE;
            auto GB = [&](int s) { return setB ? (s < 2 ? s : s + 8) : s; };
            float2 v4[4];
#pragma unroll
            for (int r = 0; r < 4; ++r) v4[r] = st[gidx_f(Lm1[r], g, setB)];
#pragma unroll
            for (int r = 0; r < 4; ++r) { ar[r] = v4[r].x; ai[r] = v4[r].y; }
            // phase 1 (M1): prev lane 2..5, reg 8,9
            lane_gate(ar, ai, sU[c][pl][GB(2)], lane, 2);
            lane_gate(ar, ai, sU[c][pl][GB(3)], lane, 3);
            lane_gate(ar, ai, sU[c][pl][GB(4)], lane, 4);
            lane_gate(ar, ai, sU[c][pl][GB(5)], lane, 5);
            reg_gate<1>(ar, ai, sU[c][pl][GB(8)]);
            reg_gate<2>(ar, ai, sU[c][pl][GB(9)]);
            // rotate M1 -> M2
#pragma unroll
            for (int r = 0; r < 4; ++r) { sre[Lm1[r]] = ar[r]; sim[Lm1[r]] = ai[r]; }
            __syncthreads();
#pragma unroll
            for (int r = 0; r < 4; ++r) { ar[r] = sre[Lm2[r]]; ai[r] = sim[Lm2[r]]; }
            // phase 2 (M2): prev reg 6,7; CZ; next lane 0..5 + reg 6,7
            reg_gate<1>(ar, ai, sU[c][pl][GB(6)]);
            reg_gate<2>(ar, ai, sU[c][pl][GB(7)]);
#pragma unroll
            for (int r = 0; r < 4; ++r)
                if (cz_neg(gidx_f(Lm2[r], g, setB))) { ar[r] = -ar[r]; ai[r] = -ai[r]; }
            lane_gate(ar, ai, sU[c][nl][GB(0)], lane, 0);
            lane_gate(ar, ai, sU[c][nl][GB(1)], lane, 1);
            lane_gate(ar, ai, sU[c][nl][GB(2)], lane, 2);
            lane_gate(ar, ai, sU[c][nl][GB(3)], lane, 3);
            lane_gate(ar, ai, sU[c][nl][GB(4)], lane, 4);
            lane_gate(ar, ai, sU[c][nl][GB(5)], lane, 5);
            reg_gate<1>(ar, ai, sU[c][nl][GB(6)]);
            reg_gate<2>(ar, ai, sU[c][nl][GB(7)]);
            // rotate M2 -> M1
#pragma unroll
            for (int r = 0; r < 4; ++r) { sre[Lm2[r]] = ar[r]; sim[Lm2[r]] = ai[r]; }
            __syncthreads();
#pragma unroll
            for (int r = 0; r < 4; ++r) { ar[r] = sre[Lm1[r]]; ai[r] = sim[Lm1[r]]; }
            // phase 3 (M1): next reg 8,9, store
            reg_gate<1>(ar, ai, sU[c][nl][GB(8)]);
            reg_gate<2>(ar, ai, sU[c][nl][GB(9)]);
#pragma unroll
            for (int r = 0; r < 4; ++r)
                st[gidx_f(Lm1[r], g, setB)] = make_float2(ar[r], ai[r]);
        }
        grid_barrier(bar, 2 + p);
    }

    // ---- P6: delta-RX on psi1, dot with raw psi2 ----
    {
        const float2* s1 = states;
        const float2* s2 = states + NSTATE;
        float2 v1[4], v2[4];
#pragma unroll
        for (int r = 0; r < 4; ++r) {
            v1[r] = s1[(g << 10) | Lm1[r]];
            v2[r] = s2[(g << 10) | Lm2[r]];
        }
#pragma unroll
        for (int r = 0; r < 4; ++r) { ar[r] = v1[r].x; ai[r] = v1[r].y; }
        lane_gate(ar, ai, sDel[0], lane, 2);
        lane_gate(ar, ai, sDel[1], lane, 3);
        lane_gate(ar, ai, sDel[2], lane, 4);
        lane_gate(ar, ai, sDel[3], lane, 5);
        reg_gate<1>(ar, ai, sDel[6]);
        reg_gate<2>(ar, ai, sDel[7]);
#pragma unroll
        for (int r = 0; r < 4; ++r) { sre[Lm1[r]] = ar[r]; sim[Lm1[r]] = ai[r]; }
        __syncthreads();
#pragma unroll
        for (int r = 0; r < 4; ++r) { ar[r] = sre[Lm2[r]]; ai[r] = sim[Lm2[r]]; }
        reg_gate<1>(ar, ai, sDel[4]);
        reg_gate<2>(ar, ai, sDel[5]);
        double accr = 0.0, acci = 0.0;
#pragma unroll
        for (int r = 0; r < 4; ++r) {
            accr += (double)v2[r].x * ar[r] + (double)v2[r].y * ai[r];
            acci += (double)v2[r].x * ai[r] - (double)v2[r].y * ar[r];
        }
        for (int o = 32; o > 0; o >>= 1) {
            accr += __shfl_down(accr, o, 64);
            acci += __shfl_down(acci, o, 64);
        }
        if (lane == 0) { wr[wave] = accr; wi[wave] = acci; }
        __syncthreads();
        if (t == 0) {
            double br = wr[0] + wr[1] + wr[2] + wr[3];
            double bi = wi[0] + wi[1] + wi[2] + wi[3];
            atomicAdd(&acc[0], br);
            atomicAdd(&acc[1], bi);
            __threadfence();
            unsigned old = atomicAdd(cnt2, 1u);
            if (old == NBLK - 1) {
                double fr = atomicAdd(&acc[0], 0.0);
                double fi = atomicAdd(&acc[1], 0.0);
                out[0] = (float)(fr * fr + fi * fi);
            }
        }
    }
}

// ---------------- launch ----------------------------------------------------
extern "C" void kernel_launch(void* const* d_in, const int* in_sizes, int n_in,
                              void* d_out, int out_size, void* d_ws, size_t ws_size,
                              hipStream_t stream)
{
    const float* x1 = (const float*)d_in[0];
    const float* x2 = (const float*)d_in[1];
    const float* iscale = (const float*)d_in[2];
    const float* var = (const float*)d_in[3];
    float* out = (float*)d_out;

    // ws layout (separate cache lines): [8192] bar; [8320] acc (2 doubles);
    // [8448] cnt2; [16384, 16384+4MB) statevectors.
    unsigned* bar    = (unsigned*)((char*)d_ws + 8192);
    double*   acc    = (double*)((char*)d_ws + 8320);
    unsigned* cnt2   = (unsigned*)((char*)d_ws + 8448);
    float2*   states = (float2*)((char*)d_ws + 16384);

    // zero barrier/accumulator state (graph-capturable memset node)
    hipMemsetAsync((char*)d_ws + 8192, 0, 512, stream);

    mega_kernel<<<NBLK, TPB, 0, stream>>>(states, x1, x2, iscale, var,
                                          bar, acc, cnt2, out);
}

// Round 7
// 100.184 us; speedup vs baseline: 3.7425x; 2.6544x over previous
//
#include <hip/hip_runtime.h>
#include <math.h>

// 18-qubit statevector, 2 circuits + |<psi2|psi1>|^2, TWO kernels, no grid
// barriers. Qubit q (reference) <-> global index bit (17-q). CZ chain is
// diagonal: per-layer fold = parity(popc(i & (i>>1) & M)) with static masks.
//
// Light-cone (trapezoid) schedule:
//  Phase 1 (window qubits 0..10 = bits 7..17): since qubits 11..17 are |0>,
//    the state lives on 2048 amps -> every block recomputes it locally in LDS
//    (product init incl. L0, then L1 on q0..9, L2 0..8, L3 0..7, L4 0..6,
//    dRX(psi1) q0..5, with CZ0..CZ4 partial folds, masks bits 7+m..16).
//  Phase 2 (window bits 0..10, chunk bits 11..17; 128 chunks x 2 circ = 256
//    blocks): L0 q11..17, L1 q10..17, L2 q9..17, L3 q8..17, L4 q7..17,
//    dRX(psi1) q7..17; CZ_m folds masks bits 0..6+m (CZ4 split 0x71F/0xE0).
//  Final L5 RY*RZ and CZ5 cancel in the overlap (verified R4); only
//    dRX(q)=RX(iscale*(x1-x2)) remains, applied to psi1. The orphan dRX(q6)
//    (bit 11 = chunk bit) folds into the dot kernel via the cross term
//    conj(psi2[i]) * (c*psi1[i] - i*s*psi1[i^2048]).
//
// Per block: 2048 amps, 256 thr, 8 amps/thread (3 reg bits); lane bits via
// shfl_xor, wave bits via LDS rotations (XOR bank swizzle), ~10 rotations.

#define NQ      18
#define NSTATE  (1 << NQ)
#define TPB     256

__device__ __forceinline__ int SW(int i) { return i ^ ((i >> 5) & 31); }

__device__ __forceinline__ float2 cmulf(float2 a, float2 b) {
    return make_float2(a.x * b.x - a.y * b.y, a.x * b.y + a.y * b.x);
}

__device__ __forceinline__ void compose_U(double cx, double sx, double cy,
                                          double sy, double zc, double zs,
                                          float2* up)
{
    double m00r = cy * cx,  m00i =  sy * sx;
    double m01r = -sy * cx, m01i = -cy * sx;
    double m10r = sy * cx,  m10i = -cy * sx;
    double m11r = cy * cx,  m11i = -sy * sx;
    up[0] = make_float2((float)(m00r * zc + m00i * zs), (float)(m00i * zc - m00r * zs));
    up[1] = make_float2((float)(m01r * zc + m01i * zs), (float)(m01i * zc - m01r * zs));
    up[2] = make_float2((float)(m10r * zc - m10i * zs), (float)(m10i * zc + m10r * zs));
    up[3] = make_float2((float)(m11r * zc - m11i * zs), (float)(m11i * zc + m11r * zs));
}

__device__ __forceinline__ void cpair(
    float& a0r, float& a0i, float& a1r, float& a1i,
    float u00r, float u00i, float u01r, float u01i,
    float u10r, float u10i, float u11r, float u11i)
{
    float n0r = u00r * a0r - u00i * a0i + u01r * a1r - u01i * a1i;
    float n0i = u00r * a0i + u00i * a0r + u01r * a1i + u01i * a1r;
    float n1r = u10r * a0r - u10i * a0i + u11r * a1r - u11i * a1i;
    float n1i = u10r * a0i + u10i * a0r + u11r * a1i + u11i * a1r;
    a0r = n0r; a0i = n0i; a1r = n1r; a1i = n1i;
}

template<int RB>
__device__ __forceinline__ void reg_gate8(float (&ar)[8], float (&ai)[8],
                                          const float2* up)
{
    float u00r = up[0].x, u00i = up[0].y, u01r = up[1].x, u01i = up[1].y;
    float u10r = up[2].x, u10i = up[2].y, u11r = up[3].x, u11i = up[3].y;
#pragma unroll
    for (int r = 0; r < 8; ++r) {
        if (r & RB) continue;
        int r1 = r | RB;
        cpair(ar[r], ai[r], ar[r1], ai[r1],
              u00r, u00i, u01r, u01i, u10r, u10i, u11r, u11i);
    }
}

__device__ __forceinline__ void lane_gate8(float (&ar)[8], float (&ai)[8],
                                           const float2* up, int lane, int j)
{
    float u00r = up[0].x, u00i = up[0].y, u01r = up[1].x, u01i = up[1].y;
    float u10r = up[2].x, u10i = up[2].y, u11r = up[3].x, u11i = up[3].y;
    int side = (lane >> j) & 1;
    float car = side ? u11r : u00r, cai = side ? u11i : u00i;
    float cbr = side ? u10r : u01r, cbi = side ? u10i : u01i;
#pragma unroll
    for (int r = 0; r < 8; ++r) {
        float pr = __shfl_xor(ar[r], 1 << j, 64);
        float pi = __shfl_xor(ai[r], 1 << j, 64);
        float mr = ar[r], mi = ai[r];
        ar[r] = car * mr - cai * mi + cbr * pr - cbi * pi;
        ai[r] = car * mi + cai * mr + cbr * pi + cbi * pr;
    }
}

// ---------------- the simulation kernel ------------------------------------
__global__ __launch_bounds__(TPB) void sim_kernel(
    float2* __restrict__ states,
    const float* __restrict__ x1, const float* __restrict__ x2,
    const float* __restrict__ iscale, const float* __restrict__ var,
    double* __restrict__ acc, unsigned* __restrict__ cnt)
{
    __shared__ float sre[2048], sim_[2048];
    __shared__ float2 sUa[5 * 11 * 4];   // phase-1 gates: [l][w], q = 10-w
    __shared__ float2 sUb[5 * 11 * 4];   // phase-2 gates: [l][w], q = 17-w
    __shared__ float2 sDa[6 * 4];        // dRX, phase-1: j -> w=5+j, q=5-j
    __shared__ float2 sDb[11 * 4];       // dRX, phase-2: w -> q=17-w

    int blk = blockIdx.x, t = threadIdx.x, lane = t & 63, wave = t >> 6;
    int c = blk >> 7, gc = blk & 127;
    const float* xv = c ? x2 : x1;

    if (blk == 0 && t == 0) { acc[0] = 0.0; acc[1] = 0.0; *cnt = 0u; }

    // ---- compose gate matrices (fp64 sincos) ----
    if (t < 110) {
        int which = t >= 55;
        int tt = which ? t - 55 : t;
        int l = tt / 11, w = tt % 11;
        int q = which ? (17 - w) : (10 - w);
        double tx = (double)iscale[l * NQ + q] * (double)xv[q];
        double ty = (double)var[l * 2 * NQ + q];
        double tz = (double)var[l * 2 * NQ + NQ + q];
        double sx, cx, sy, cy, sz, cz;
        sincos(tx * 0.5, &sx, &cx);
        sincos(ty * 0.5, &sy, &cy);
        sincos(tz * 0.5, &sz, &cz);
        compose_U(cx, sx, cy, sy, cz, sz,
                  which ? &sUb[(l * 11 + w) * 4] : &sUa[(l * 11 + w) * 4]);
    } else if (t < 127) {
        int isb = t >= 116;
        int j = isb ? (t - 116) : (t - 110);
        int q = isb ? (17 - j) : (5 - j);
        double d = (double)iscale[5 * NQ + q] * ((double)x1[q] - (double)x2[q]);
        double sn, cs;
        sincos(d * 0.5, &sn, &cs);
        float2* up = isb ? &sDb[j * 4] : &sDa[j * 4];
        up[0] = make_float2((float)cs, 0.f);  up[1] = make_float2(0.f, (float)-sn);
        up[2] = make_float2(0.f, (float)-sn); up[3] = make_float2((float)cs, 0.f);
    }
    __syncthreads();

    float ar[8], ai[8];
    // phase-1 mappings over W (bits 7..17 of i, i = W<<7)
    auto W1 = [&](int r) { return r | (wave << 3) | (lane << 5); };
    auto W2 = [&](int r) { return wave | (r << 2) | (lane << 5); };
    // phase-2 mappings over x (bits 0..10 of i, i = (gc<<11)|x)
    auto X1 = [&](int r) { return lane | (wave << 6) | (r << 8); };
    auto X2 = [&](int r) { return lane | (r << 6) | (wave << 9); };
    auto rot = [&](auto from, auto to) {
#pragma unroll
        for (int r = 0; r < 8; ++r) { int s = SW(from(r)); sre[s] = ar[r]; sim_[s] = ai[r]; }
        __syncthreads();
#pragma unroll
        for (int r = 0; r < 8; ++r) { int s = SW(to(r)); ar[r] = sre[s]; ai[r] = sim_[s]; }
    };
    auto Ua = [&](int l, int w) -> const float2* { return &sUa[(l * 11 + w) * 4]; };
    auto Ub = [&](int l, int w) -> const float2* { return &sUb[(l * 11 + w) * 4]; };
    auto czfold = [&](unsigned M, auto gidx) {
#pragma unroll
        for (int r = 0; r < 8; ++r) {
            int i = gidx(r);
            if (__popc(i & (i >> 1) & M) & 1) { ar[r] = -ar[r]; ai[r] = -ai[r]; }
        }
    };
    auto g1_1 = [&](int r) { return W1(r) << 7; };
    auto g1_2 = [&](int r) { return W2(r) << 7; };
    auto g2_1 = [&](int r) { return (gc << 11) | X1(r); };
    auto g2_2 = [&](int r) { return (gc << 11) | X2(r); };

    // ================= PHASE 1 (every block, own circuit) ==================
    // s1 [M1a]: product init (L0 on q0..10 folded in)
    {
        float2 com = make_float2(1.f, 0.f);
        const float2* u3 = Ua(0, 3); com = cmulf(com, (wave & 1) ? u3[2] : u3[0]);
        const float2* u4 = Ua(0, 4); com = cmulf(com, (wave >> 1) ? u4[2] : u4[0]);
#pragma unroll
        for (int j = 0; j < 6; ++j) {
            const float2* u = Ua(0, 5 + j);
            com = cmulf(com, ((lane >> j) & 1) ? u[2] : u[0]);
        }
        const float2* u0 = Ua(0, 0); const float2* u1 = Ua(0, 1); const float2* u2 = Ua(0, 2);
#pragma unroll
        for (int r = 0; r < 8; ++r) {
            float2 f = cmulf((r & 1) ? u0[2] : u0[0], (r & 2) ? u1[2] : u1[0]);
            f = cmulf(f, (r & 4) ? u2[2] : u2[0]);
            f = cmulf(com, f);
            ar[r] = f.x; ai[r] = f.y;
        }
    }
    czfold(0x1FF80u, g1_1);                       // CZ0: q-pairs (0,1)..(9,10)
    reg_gate8<2>(ar, ai, Ua(1, 1));               // L1 w1
    reg_gate8<4>(ar, ai, Ua(1, 2));               // L1 w2
#pragma unroll
    for (int j = 0; j < 6; ++j) lane_gate8(ar, ai, Ua(1, 5 + j), lane, j);
    rot(W1, W2);
    // s2 [M2a]
    reg_gate8<2>(ar, ai, Ua(1, 3));
    reg_gate8<4>(ar, ai, Ua(1, 4));
    czfold(0x1FF00u, g1_2);                       // CZ1
    reg_gate8<1>(ar, ai, Ua(2, 2));
    reg_gate8<2>(ar, ai, Ua(2, 3));
    reg_gate8<4>(ar, ai, Ua(2, 4));
#pragma unroll
    for (int j = 0; j < 6; ++j) lane_gate8(ar, ai, Ua(2, 5 + j), lane, j);
    rot(W2, W1);
    // s3 [M1a]
    czfold(0x1FE00u, g1_1);                       // CZ2
#pragma unroll
    for (int j = 0; j < 6; ++j) lane_gate8(ar, ai, Ua(3, 5 + j), lane, j);
    rot(W1, W2);
    // s4 [M2a]
    reg_gate8<2>(ar, ai, Ua(3, 3));
    reg_gate8<4>(ar, ai, Ua(3, 4));
    czfold(0x1FC00u, g1_2);                       // CZ3
    reg_gate8<4>(ar, ai, Ua(4, 4));
#pragma unroll
    for (int j = 0; j < 6; ++j) lane_gate8(ar, ai, Ua(4, 5 + j), lane, j);
    rot(W2, W1);
    // s5 [M1a]
    czfold(0x1F800u, g1_1);                       // CZ4 pairs (0,1)..(5,6)
    if (c == 0) {
#pragma unroll
        for (int j = 0; j < 6; ++j) lane_gate8(ar, ai, &sDa[j * 4], lane, j);
    }
    // transition: publish phase-1 vector, sparse-gather phase-2 init
#pragma unroll
    for (int r = 0; r < 8; ++r) { int s = SW(W1(r)); sre[s] = ar[r]; sim_[s] = ai[r]; }
    __syncthreads();
#pragma unroll
    for (int r = 0; r < 8; ++r) {
        int x = X1(r);
        if ((x & 127) == 0) {
            int Wv = (gc << 4) | (x >> 7);
            int s = SW(Wv);
            ar[r] = sre[s]; ai[r] = sim_[s];
        } else { ar[r] = 0.f; ai[r] = 0.f; }
    }
    __syncthreads();   // protect LDS before first phase-2 rotation write

    // ================= PHASE 2 (chunk gc, circuit c) =======================
    // s1 [M1b]: L0 lane w0..5
#pragma unroll
    for (int j = 0; j < 6; ++j) lane_gate8(ar, ai, Ub(0, j), lane, j);
    rot(X1, X2);
    // s2 [M2b]
    reg_gate8<1>(ar, ai, Ub(0, 6));               // L0 w6
    czfold(0x7Fu, g2_2);                          // CZ0: q-pairs (10,11)..(16,17)
#pragma unroll
    for (int j = 0; j < 6; ++j) lane_gate8(ar, ai, Ub(1, j), lane, j);
    reg_gate8<1>(ar, ai, Ub(1, 6));
    reg_gate8<2>(ar, ai, Ub(1, 7));
    rot(X2, X1);
    // s3 [M1b]
    czfold(0xFFu, g2_1);                          // CZ1
#pragma unroll
    for (int j = 0; j < 6; ++j) lane_gate8(ar, ai, Ub(2, j), lane, j);
    reg_gate8<1>(ar, ai, Ub(2, 8));
    rot(X1, X2);
    // s4 [M2b]
    reg_gate8<1>(ar, ai, Ub(2, 6));
    reg_gate8<2>(ar, ai, Ub(2, 7));
    czfold(0x1FFu, g2_2);                         // CZ2
#pragma unroll
    for (int j = 0; j < 6; ++j) lane_gate8(ar, ai, Ub(3, j), lane, j);
    reg_gate8<1>(ar, ai, Ub(3, 6));
    reg_gate8<2>(ar, ai, Ub(3, 7));
    reg_gate8<4>(ar, ai, Ub(3, 8));
    rot(X2, X1);
    // s5 [M1b]
    reg_gate8<2>(ar, ai, Ub(3, 9));               // L3 w9
    czfold(0x3FFu, g2_1);                         // CZ3
#pragma unroll
    for (int j = 0; j < 6; ++j) lane_gate8(ar, ai, Ub(4, j), lane, j);
    reg_gate8<1>(ar, ai, Ub(4, 8));
    reg_gate8<2>(ar, ai, Ub(4, 9));
    reg_gate8<4>(ar, ai, Ub(4, 10));
    czfold(0x71Fu, g2_1);                         // CZ4 part: bits 0..4, 8..10
    if (c == 0) {
#pragma unroll
        for (int j = 0; j < 5; ++j) lane_gate8(ar, ai, &sDb[j * 4], lane, j);
        reg_gate8<2>(ar, ai, &sDb[9 * 4]);
        reg_gate8<4>(ar, ai, &sDb[10 * 4]);
    }
    rot(X1, X2);
    // s6 [M2b]
    reg_gate8<1>(ar, ai, Ub(4, 6));
    reg_gate8<2>(ar, ai, Ub(4, 7));
    czfold(0xE0u, g2_2);                          // CZ4 part: bits 5..7
    if (c == 0) {
        lane_gate8(ar, ai, &sDb[5 * 4], lane, 5);
        reg_gate8<1>(ar, ai, &sDb[6 * 4]);
        reg_gate8<2>(ar, ai, &sDb[7 * 4]);
        reg_gate8<4>(ar, ai, &sDb[8 * 4]);
    }
    // store (coalesced: lane = low bits)
    float2* st = states + (size_t)c * NSTATE;
#pragma unroll
    for (int r = 0; r < 8; ++r) {
        int i = (gc << 11) | X2(r);
        st[i] = make_float2(ar[r], ai[r]);
    }
}

// ---------------- dot kernel: dRX(q6) cross-term + reduction ---------------
__global__ __launch_bounds__(TPB) void dot_kernel(
    const float2* __restrict__ states,
    const float* __restrict__ x1, const float* __restrict__ x2,
    const float* __restrict__ iscale,
    double* __restrict__ acc, unsigned* __restrict__ cnt,
    float* __restrict__ out)
{
    __shared__ double wr[4], wi[4];
    int t = threadIdx.x, lane = t & 63, wave = t >> 6;
    const float2* s1 = states;
    const float2* s2 = states + NSTATE;

    double d = (double)iscale[5 * NQ + 6] * ((double)x1[6] - (double)x2[6]);
    double sn, cs;
    sincos(d * 0.5, &sn, &cs);
    float cf = (float)cs, sf = (float)sn;

    int base = (blockIdx.x * TPB + t) * 4;
    int pbase = base ^ 2048;           // flip bit 11 (qubit 6)
    double accr = 0.0, acci = 0.0;
#pragma unroll
    for (int k = 0; k < 4; ++k) {
        float2 p1 = s1[base + k], pp = s1[pbase + k], p2 = s2[base + k];
        // (dRX6 psi1)[i] = c*psi1[i] - i*s*psi1[i^b11]
        float gr = cf * p1.x + sf * pp.y;
        float gi = cf * p1.y - sf * pp.x;
        accr += (double)p2.x * gr + (double)p2.y * gi;
        acci += (double)p2.x * gi - (double)p2.y * gr;
    }
    for (int o = 32; o > 0; o >>= 1) {
        accr += __shfl_down(accr, o, 64);
        acci += __shfl_down(acci, o, 64);
    }
    if (lane == 0) { wr[wave] = accr; wi[wave] = acci; }
    __syncthreads();
    if (t == 0) {
        double br = wr[0] + wr[1] + wr[2] + wr[3];
        double bi = wi[0] + wi[1] + wi[2] + wi[3];
        atomicAdd(&acc[0], br);
        atomicAdd(&acc[1], bi);
        __threadfence();
        unsigned old = atomicAdd(cnt, 1u);
        if (old == gridDim.x - 1) {
            double fr = atomicAdd(&acc[0], 0.0);
            double fi = atomicAdd(&acc[1], 0.0);
            out[0] = (float)(fr * fr + fi * fi);
        }
    }
}

// ---------------- launch ----------------------------------------------------
extern "C" void kernel_launch(void* const* d_in, const int* in_sizes, int n_in,
                              void* d_out, int out_size, void* d_ws, size_t ws_size,
                              hipStream_t stream)
{
    const float* x1 = (const float*)d_in[0];
    const float* x2 = (const float*)d_in[1];
    const float* iscale = (const float*)d_in[2];
    const float* var = (const float*)d_in[3];
    float* out = (float*)d_out;

    // ws layout: [8192] acc (2 doubles); [8320] cnt; [16384,+4MB) statevectors
    double*   acc    = (double*)((char*)d_ws + 8192);
    unsigned* cnt    = (unsigned*)((char*)d_ws + 8320);
    float2*   states = (float2*)((char*)d_ws + 16384);

    sim_kernel<<<256, TPB, 0, stream>>>(states, x1, x2, iscale, var, acc, cnt);
    dot_kernel<<<NSTATE / (TPB * 4), TPB, 0, stream>>>(states, x1, x2, iscale,
                                                       acc, cnt, out);
}